// Round 2
// baseline (84.189 us; speedup 1.0000x reference)
//
#include <hip/hip_runtime.h>

// DistillKL 'w' branch forward, B=64, C=1000, T=4.
// Key identity: with xm[k] = (w[k] ? x[k] : +1e30),
//   sum_k w[k]*relu(x[i]-x[k]) = C*x[i] - sum_k min(x[i], xm[k])
// (unmasked k: min(xi,1e30)=xi cancels the C*xi term exactly).
// => inner loop is 2 VALU (v_min + v_add) per k per tensor.

#define BN 64
#define CN 1000
#define SPLITS 8
#define CHUNK 125          // ceil(1000/8)
#define THREADS 128
#define NEG_LOG_EPS -16.118095650958319f   // log(1e-7)

__global__ __launch_bounds__(THREADS) void distill_part(
    const float* __restrict__ ys, const float* __restrict__ yt,
    const float* __restrict__ w, float* __restrict__ part)
{
    const int b = blockIdx.x;
    const int s = blockIdx.y;
    const int tid = threadIdx.x;
    const int lane = tid & 63;
    const int wid = tid >> 6;          // 2 waves per block

    __shared__ float2 xm[CN];          // (masked xs, masked xt): w? x : +1e30
    __shared__ float redns[4];         // neg_sum reduction (2 waves x 2 sums)
    __shared__ float redterm[2];       // loss-term reduction

    const float* ysr = ys + b * CN;
    const float* ytr = yt + b * CN;
    const float* wr  = w  + b * CN;

    float ns_s = 0.f, ns_t = 0.f;
    for (int k = tid; k < CN; k += THREADS) {
        float a  = ysr[k] * 0.25f;
        float c2 = ytr[k] * 0.25f;
        float wk = wr[k];
        bool pos = (wk != 0.f);
        xm[k] = make_float2(pos ? a : 1e30f, pos ? c2 : 1e30f);
        float nw = 1.f - wk;
        ns_s += nw * __expf(a);
        ns_t += nw * __expf(c2);
    }
    #pragma unroll
    for (int off = 32; off > 0; off >>= 1) {
        ns_s += __shfl_down(ns_s, off);
        ns_t += __shfl_down(ns_t, off);
    }
    if (lane == 0) { redns[wid * 2] = ns_s; redns[wid * 2 + 1] = ns_t; }
    __syncthreads();
    const float negsum_s = redns[0] + redns[2];
    const float negsum_t = redns[1] + redns[3];

    float term = 0.f;
    const int i = s * CHUNK + tid;
    if (tid < CHUNK && i < CN) {
        const float xsi = ysr[i] * 0.25f;
        const float xti = ytr[i] * 0.25f;
        const float wi  = wr[i];
        // 4 independent accumulator pairs to break the add chains
        float as0 = 0.f, as1 = 0.f, as2 = 0.f, as3 = 0.f;
        float at0 = 0.f, at1 = 0.f, at2 = 0.f, at3 = 0.f;
        for (int k = 0; k < CN; k += 4) {      // 1000 % 4 == 0
            float2 m0 = xm[k + 0];
            float2 m1 = xm[k + 1];
            float2 m2 = xm[k + 2];
            float2 m3 = xm[k + 3];
            as0 += fminf(xsi, m0.x);  at0 += fminf(xti, m0.y);
            as1 += fminf(xsi, m1.x);  at1 += fminf(xti, m1.y);
            as2 += fminf(xsi, m2.x);  at2 += fminf(xti, m2.y);
            as3 += fminf(xsi, m3.x);  at3 += fminf(xti, m3.y);
        }
        const float acc_s = (as0 + as1) + (as2 + as3);
        const float acc_t = (at0 + at1) + (at2 + at3);
        // t3 = (C*xi - acc) / C = xi - acc/C
        const float t3s = xsi - acc_s * (1.0f / CN);
        const float t3t = xti - acc_t * (1.0f / CN);
        const float ch_s = wi * __expf(-t3s) + (1.f - wi);
        const float ch_t = wi * __expf(-t3t) + (1.f - wi);
        const float exs = __expf(xsi), ext = __expf(xti);
        const float p_s = exs / (ch_s * negsum_s + exs);
        const float p_t = ext / (ch_t * negsum_t + ext);
        const float ps1 = fminf(p_s, 1.f);
        const float pt1 = fminf(p_t, 1.f);
        const float vpos = fminf(fabsf((pt1 + 1.f) * 0.5f - ps1), 1.f);
        const float vneg = fminf(fabsf(pt1 * 0.5f - ps1), 1.f);
        const float expt = wi * sqrtf(sqrtf(vpos)) + (1.f - wi) * vneg;
        const float logps = fmaxf(expt * __logf(ps1), NEG_LOG_EPS);
        term = fmaxf(p_t, 1e-7f) * logps;
    }
    #pragma unroll
    for (int off = 32; off > 0; off >>= 1) term += __shfl_down(term, off);
    if (lane == 0) redterm[wid] = term;
    __syncthreads();
    if (tid == 0) part[b * SPLITS + s] = redterm[0] + redterm[1];
}

__global__ __launch_bounds__(64) void distill_final(
    const float* __restrict__ part, float* __restrict__ out)
{
    const int t = threadIdx.x;
    float v = 0.f;
    for (int j = t; j < BN * SPLITS; j += 64) v += part[j];
    #pragma unroll
    for (int off = 32; off > 0; off >>= 1) v += __shfl_down(v, off);
    if (t == 0) out[0] = -0.25f * v;    // -(T*T)/B = -16/64
}

extern "C" void kernel_launch(void* const* d_in, const int* in_sizes, int n_in,
                              void* d_out, int out_size, void* d_ws, size_t ws_size,
                              hipStream_t stream) {
    const float* ys = (const float*)d_in[0];
    const float* yt = (const float*)d_in[1];
    const float* w  = (const float*)d_in[2];
    float* out  = (float*)d_out;
    float* part = (float*)d_ws;   // BN*SPLITS floats

    dim3 grid(BN, SPLITS);
    distill_part<<<grid, THREADS, 0, stream>>>(ys, yt, w, part);
    distill_final<<<1, 64, 0, stream>>>(part, out);
}